// Round 3
// baseline (440.979 us; speedup 1.0000x reference)
//
#include <hip/hip_runtime.h>
#include <math.h>

// EGNN fused kernel, round 3.
// Changes vs r2: (1) __launch_bounds__(256,4) -> cap total regs 128/wave so
// 4 blocks/CU fit (r2 ran at 2: unified VGPR+AGPR file put us at ~256/wave).
// (2) wave's two output columns are ADJACENT (uc, uc+1): epilogue packs pairs
// with v_cvt_pk_bf16_f32 (1 op / 2 vals) and stores ds_write_b32 (8 stores,
// 2-way bank aliasing = free) instead of 16 f2bf(4 ops) + 16 ds_write_b16.

#define BB    2
#define NN    512
#define HDIM  64
#define UDIM  128
#define JT    32
#define NTILE (NN / JT)
#define FP    72    // F row pitch (ushort), 144B
#define PP    136   // P row pitch (ushort), 272B

typedef float f32x4 __attribute__((ext_vector_type(4)));
typedef short s16x8 __attribute__((ext_vector_type(8)));

__device__ __forceinline__ ushort f2bf(float f) {          // setup-path only
    union { float f; unsigned u; } v; v.f = f;
    return (ushort)((v.u + 0x7FFFu + ((v.u >> 16) & 1u)) >> 16);
}
__device__ __forceinline__ float bf2f(ushort s) {
    union { unsigned u; float f; } v; v.u = ((unsigned)s) << 16; return v.f;
}
__device__ __forceinline__ unsigned pk2(float lo, float hi) {  // bf16(lo) | bf16(hi)<<16
    unsigned r;
    asm("v_cvt_pk_bf16_f32 %0, %1, %2" : "=v"(r) : "v"(lo), "v"(hi));
    return r;
}
__device__ __forceinline__ f32x4 MFMA(s16x8 a, s16x8 b, f32x4 c) {
    return __builtin_amdgcn_mfma_f32_16x16x32_bf16(a, b, c, 0, 0, 0);
}
__device__ __forceinline__ float eluf(float v) { return v > 0.f ? v : __expf(v) - 1.f; }

// B-fragment gather: dst[s][n] holds W[32s+8q+ii][uc0+n], n in {0,1}
__device__ __forceinline__ void load_wfrags(const float* __restrict__ W, int q, int uc0,
                                            s16x8 (&dst)[4][2]) {
#pragma unroll
    for (int s = 0; s < 4; ++s)
#pragma unroll
        for (int n = 0; n < 2; ++n) {
            s16x8 r;
#pragma unroll
            for (int ii = 0; ii < 8; ++ii)
                r[ii] = (short)f2bf(W[(32 * s + 8 * q + ii) * UDIM + uc0 + n]);
            dst[s][n] = r;
        }
}

template <int KSTEPS, int PITCH>
__device__ __forceinline__ void gemm_P(const ushort* __restrict__ P, const s16x8 (&wB)[KSTEPS][2],
                                       int l15, int q, f32x4 (&acc)[2][2]) {
#pragma unroll
    for (int s = 0; s < KSTEPS; ++s) {
        const s16x8 a0 = *(const s16x8*)(P + l15 * PITCH + 32 * s + 8 * q);
        const s16x8 a1 = *(const s16x8*)(P + (16 + l15) * PITCH + 32 * s + 8 * q);
        acc[0][0] = MFMA(a0, wB[s][0], acc[0][0]);
        acc[0][1] = MFMA(a0, wB[s][1], acc[0][1]);
        acc[1][0] = MFMA(a1, wB[s][0], acc[1][0]);
        acc[1][1] = MFMA(a1, wB[s][1], acc[1][1]);
    }
}

// packed store: cols (uc0, uc0+1) as one b32 per row; 8 stores/thread
template <bool ELU>
__device__ __forceinline__ void store_P(ushort* __restrict__ P, const f32x4 (&v)[2][2],
                                        int q, int uc0) {
#pragma unroll
    for (int m = 0; m < 2; ++m)
#pragma unroll
        for (int r = 0; r < 4; ++r) {
            const int row = 16 * m + 4 * q + r;
            float a = v[m][0][r], c = v[m][1][r];
            if (ELU) { a = eluf(a); c = eluf(c); }
            *(unsigned*)(P + row * PP + uc0) = pk2(a, c);
        }
}

__global__ __launch_bounds__(256, 4) void egnn_mfma(
    const float* __restrict__ x, const float* __restrict__ h,
    const float* __restrict__ We1, const float* __restrict__ be1,
    const float* __restrict__ We2, const float* __restrict__ be2,
    const float* __restrict__ Winf, const float* __restrict__ binf,
    const float* __restrict__ Wx1, const float* __restrict__ bx1,
    const float* __restrict__ Wx2, const float* __restrict__ bx2,
    const float* __restrict__ Wx3, const float* __restrict__ bx3,
    const float* __restrict__ Wh1, const float* __restrict__ bh1,
    const float* __restrict__ Wh2, const float* __restrict__ bh2,
    const float* __restrict__ Wout, const float* __restrict__ bout,
    float* __restrict__ out) {
    __shared__ ushort F[JT][FP];
    __shared__ ushort P1[JT][PP];
    __shared__ ushort P2[JT][PP];
    __shared__ float normL[JT];
    __shared__ float diffL[JT][3];
    __shared__ float rpart[8][JT];
    __shared__ float eL[JT];
    __shared__ float bias1L[UDIM];
    __shared__ float WinfL[UDIM], Wx3L[UDIM];
    __shared__ float catL[UDIM + HDIM];
    __shared__ float th1[UDIM], th2[UDIM];

    const int bi = blockIdx.x;
    const int b  = bi >> 9;
    const int i  = bi & (NN - 1);
    const int tid  = threadIdx.x;
    const int lane = tid & 63;
    const int w    = tid >> 6;
    const int l15  = lane & 15;
    const int q    = lane >> 4;
    const int uc0  = 32 * w + 2 * l15;     // adjacent output columns uc0, uc0+1

    // ---- per-block setup ----
    s16x8 wB1[2][2];
#pragma unroll
    for (int s = 0; s < 2; ++s)
#pragma unroll
        for (int n = 0; n < 2; ++n) {
            s16x8 r;
#pragma unroll
            for (int ii = 0; ii < 8; ++ii)
                r[ii] = (short)f2bf(We1[(1 + 32 * s + 8 * q + ii) * UDIM + uc0 + n]);
            wB1[s][n] = r;
        }
    s16x8 wB2[4][2], wB3[4][2], wB4[4][2];
    load_wfrags(We2, q, uc0, wB2);
    load_wfrags(Wx1, q, uc0, wB3);
    load_wfrags(Wx2, q, uc0, wB4);

    if (tid < UDIM) {
        WinfL[tid] = Winf[tid];
        Wx3L[tid]  = Wx3[tid];
        float s = be1[tid];
        const float* hi = &h[(b * NN + i) * HDIM];
#pragma unroll 8
        for (int k = 0; k < HDIM; ++k)
            s = fmaf(hi[k], We1[(1 + HDIM + k) * UDIM + tid], s);
        bias1L[tid] = s;
    }
    const float w0n0 = We1[uc0], w0n1 = We1[uc0 + 1];
    const float b2n0 = be2[uc0], b2n1 = be2[uc0 + 1];
    const float bqn0 = bx1[uc0], bqn1 = bx1[uc0 + 1];
    const float brn0 = bx2[uc0], brn1 = bx2[uc0 + 1];
    const float binf0 = binf[0], bx30 = bx3[0];
    const float xi0 = x[(b * NN + i) * 3 + 0];
    const float xi1 = x[(b * NN + i) * 3 + 1];
    const float xi2 = x[(b * NN + i) * 3 + 2];
    __syncthreads();
    const float b1n0 = bias1L[uc0], b1n1 = bias1L[uc0 + 1];

    float mi0 = 0.f, mi1 = 0.f;
    float sh0 = 0.f, sh1 = 0.f, sh2 = 0.f;

    for (int t = 0; t < NTILE; ++t) {
        const int j0 = t * JT;
        __syncthreads();  // (A)

        // ---- stage h_j -> F (bf16, packed), diffs/norms ----
        {
            const int j = tid >> 3, k0 = (tid & 7) * 8;
            const float* hp = &h[(b * NN + j0 + j) * HDIM + k0];
            const float4 f0 = *(const float4*)hp;
            const float4 f1 = *(const float4*)(hp + 4);
            uint4 pv;
            pv.x = pk2(f0.x, f0.y); pv.y = pk2(f0.z, f0.w);
            pv.z = pk2(f1.x, f1.y); pv.w = pk2(f1.z, f1.w);
            *(uint4*)&F[j][k0] = pv;
        }
        if (tid < JT) {
            const int j = j0 + tid;
            float d0 = x[(b * NN + j) * 3 + 0] - xi0;
            float d1 = x[(b * NN + j) * 3 + 1] - xi1;
            float d2 = x[(b * NN + j) * 3 + 2] - xi2;
            if (j == i) { d0 = 0.f; d1 = 0.f; d2 = 0.f; }
            diffL[tid][0] = d0; diffL[tid][1] = d1; diffL[tid][2] = d2;
            normL[tid] = (j == i) ? 0.f : sqrtf(d0 * d0 + d1 * d1 + d2 * d2);
        }
        __syncthreads();  // (B)

        // ---- GEMM1 ----
        f32x4 acc[2][2];
#pragma unroll
        for (int m = 0; m < 2; ++m)
#pragma unroll
            for (int r = 0; r < 4; ++r) {
                const float nrm = normL[16 * m + 4 * q + r];
                acc[m][0][r] = fmaf(nrm, w0n0, b1n0);
                acc[m][1][r] = fmaf(nrm, w0n1, b1n1);
            }
        gemm_P<2, FP>(&F[0][0], wB1, l15, q, acc);
        store_P<true>(&P1[0][0], acc, q, uc0);
        __syncthreads();  // (C)

        // ---- GEMM2: m_ij (masked) ----
        f32x4 macc[2][2];
#pragma unroll
        for (int m = 0; m < 2; ++m)
#pragma unroll
            for (int r = 0; r < 4; ++r) { macc[m][0][r] = b2n0; macc[m][1][r] = b2n1; }
        gemm_P<4, PP>(&P1[0][0], wB2, l15, q, macc);
#pragma unroll
        for (int m = 0; m < 2; ++m)
#pragma unroll
            for (int r = 0; r < 4; ++r)
                if (j0 + 16 * m + 4 * q + r == i) { macc[m][0][r] = 0.f; macc[m][1][r] = 0.f; }
        store_P<false>(&P2[0][0], macc, q, uc0);
        __syncthreads();  // (D)

        // ---- e partials + GEMM3 ----
        {
            const int j = tid & 31, uch = tid >> 5, u0 = uch * 16;
            const s16x8 m0 = *(const s16x8*)&P2[j][u0];
            const s16x8 m1 = *(const s16x8*)&P2[j][u0 + 8];
            float p = 0.f;
#pragma unroll
            for (int c = 0; c < 8; ++c) p = fmaf(bf2f((ushort)m0[c]), WinfL[u0 + c], p);
#pragma unroll
            for (int c = 0; c < 8; ++c) p = fmaf(bf2f((ushort)m1[c]), WinfL[u0 + 8 + c], p);
            rpart[uch][j] = p;
        }
        f32x4 qacc[2][2];
#pragma unroll
        for (int m = 0; m < 2; ++m)
#pragma unroll
            for (int r = 0; r < 4; ++r) { qacc[m][0][r] = bqn0; qacc[m][1][r] = bqn1; }
        gemm_P<4, PP>(&P2[0][0], wB3, l15, q, qacc);
        store_P<true>(&P1[0][0], qacc, q, uc0);
        __syncthreads();  // (E)

        // ---- e final + GEMM4 ----
        if (tid < 32) {
            float s = 0.f;
#pragma unroll
            for (int p = 0; p < 8; ++p) s += rpart[p][tid];
            float e = 1.f / (1.f + __expf(-(s + binf0)));
            if (j0 + tid == i) e = 0.f;
            eL[tid] = e;
        }
        f32x4 racc[2][2];
#pragma unroll
        for (int m = 0; m < 2; ++m)
#pragma unroll
            for (int r = 0; r < 4; ++r) { racc[m][0][r] = brn0; racc[m][1][r] = brn1; }
        gemm_P<4, PP>(&P1[0][0], wB4, l15, q, racc);
        store_P<true>(&P2[0][0], racc, q, uc0);
        __syncthreads();  // (F)

        // ---- phi partials ; m_i accumulation ----
        {
            const int j = tid & 31, uch = tid >> 5, u0 = uch * 16;
            const s16x8 m0 = *(const s16x8*)&P2[j][u0];
            const s16x8 m1 = *(const s16x8*)&P2[j][u0 + 8];
            float p = 0.f;
#pragma unroll
            for (int c = 0; c < 8; ++c) p = fmaf(bf2f((ushort)m0[c]), Wx3L[u0 + c], p);
#pragma unroll
            for (int c = 0; c < 8; ++c) p = fmaf(bf2f((ushort)m1[c]), Wx3L[u0 + 8 + c], p);
            rpart[uch][j] = p;
        }
#pragma unroll
        for (int m = 0; m < 2; ++m)
#pragma unroll
            for (int r = 0; r < 4; ++r) {
                const float e = eL[16 * m + 4 * q + r];
                mi0 = fmaf(macc[m][0][r], e, mi0);
                mi1 = fmaf(macc[m][1][r], e, mi1);
            }
        __syncthreads();  // (G)

        // ---- phi final + shift (waves 0) ----
        if (tid < 64) {
            const int l = tid & 31;
            float s = 0.f;
#pragma unroll
            for (int p = 0; p < 8; ++p) s += rpart[p][l];
            s += bx30;
            if (j0 + l == i) s = 0.f;
            float v0 = 0.f, v1 = 0.f, v2 = 0.f;
            if (tid < 32) {
                v0 = diffL[l][0] * s; v1 = diffL[l][1] * s; v2 = diffL[l][2] * s;
            }
#pragma unroll
            for (int d = 1; d < 64; d <<= 1) {
                v0 += __shfl_xor(v0, d);
                v1 += __shfl_xor(v1, d);
                v2 += __shfl_xor(v2, d);
            }
            sh0 += v0; sh1 += v1; sh2 += v2;
        }
    }

    __syncthreads();
    // ---- m_i cross-quarter reduce -> catL ----
    {
        float v0 = mi0, v1 = mi1;
        v0 += __shfl_xor(v0, 16); v0 += __shfl_xor(v0, 32);
        v1 += __shfl_xor(v1, 16); v1 += __shfl_xor(v1, 32);
        if (lane < 16) {
            catL[uc0]     = v0;
            catL[uc0 + 1] = v1;
        }
    }
    if (tid >= 128 && tid < 128 + HDIM)
        catL[UDIM + tid - 128] = h[(b * NN + i) * HDIM + (tid - 128)];
    if (tid == 0) {
        const float inv = 1.f / (float)(NN - 1);
        out[(b * NN + i) * 3 + 0] = x[(b * NN + i) * 3 + 0] + sh0 * inv;
        out[(b * NN + i) * 3 + 1] = x[(b * NN + i) * 3 + 1] + sh1 * inv;
        out[(b * NN + i) * 3 + 2] = x[(b * NN + i) * 3 + 2] + sh2 * inv;
    }
    __syncthreads();

    // ---- h-MLP epilogue (fp32) ----
    if (tid < UDIM) {
        float s = bh1[tid];
        for (int k = 0; k < UDIM + HDIM; ++k) s = fmaf(catL[k], Wh1[k * UDIM + tid], s);
        th1[tid] = eluf(s);
    }
    __syncthreads();
    if (tid < UDIM) {
        float s = bh2[tid];
        for (int k = 0; k < UDIM; ++k) s = fmaf(th1[k], Wh2[k * UDIM + tid], s);
        th2[tid] = s;
    }
    __syncthreads();
    if (tid < HDIM) {
        float s = bout[tid];
        for (int k = 0; k < UDIM; ++k) s = fmaf(th2[k], Wout[k * HDIM + tid], s);
        out[BB * NN * 3 + (b * NN + i) * HDIM + tid] = s;
    }
}

extern "C" void kernel_launch(void* const* d_in, const int* in_sizes, int n_in,
                              void* d_out, int out_size, void* d_ws, size_t ws_size,
                              hipStream_t stream) {
    const float* x    = (const float*)d_in[0];
    const float* h    = (const float*)d_in[1];
    const float* We1  = (const float*)d_in[2];
    const float* be1  = (const float*)d_in[3];
    const float* We2  = (const float*)d_in[4];
    const float* be2  = (const float*)d_in[5];
    const float* Winf = (const float*)d_in[6];
    const float* binf = (const float*)d_in[7];
    const float* Wx1  = (const float*)d_in[8];
    const float* bx1  = (const float*)d_in[9];
    const float* Wx2  = (const float*)d_in[10];
    const float* bx2  = (const float*)d_in[11];
    const float* Wx3  = (const float*)d_in[12];
    const float* bx3  = (const float*)d_in[13];
    const float* Wh1  = (const float*)d_in[14];
    const float* bh1  = (const float*)d_in[15];
    const float* Wh2  = (const float*)d_in[16];
    const float* bh2  = (const float*)d_in[17];
    const float* Wout = (const float*)d_in[18];
    const float* bout = (const float*)d_in[19];
    float* out = (float*)d_out;

    hipLaunchKernelGGL(egnn_mfma, dim3(BB * NN), dim3(256), 0, stream,
                       x, h, We1, be1, We2, be2, Winf, binf, Wx1, bx1, Wx2, bx2,
                       Wx3, bx3, Wh1, bh1, Wh2, bh2, Wout, bout, out);
}

// Round 4
// 141.231 us; speedup vs baseline: 3.1224x; 3.1224x over previous
//
#include <hip/hip_runtime.h>
#include <math.h>

// EGNN fused kernel, round 4.
// vs r3: (1) REVERT launch bounds to (256,2) — the (256,4) reg cap spilled the
// 112-VGPR weight fragments to scratch (FETCH 12->946MB, 2.8x slower).
// (2) JT 32->64: halves barrier count (7/tile, 8 tiles) and per-tile fixed
// costs; each GEMM phase is now 16 ds_read_b128 + 32 MFMA per wave, so
// dependency chains amortize better at 2 waves/SIMD.
// Keeps r3's adjacent-column pk2 (v_cvt_pk_bf16_f32) packed b32 stores.

#define BB    2
#define NN    512
#define HDIM  64
#define UDIM  128
#define JT    64
#define NTILE (NN / JT)
#define FP    72    // F row pitch (ushort), 144B
#define PP    136   // P row pitch (ushort), 272B

typedef float f32x4 __attribute__((ext_vector_type(4)));
typedef short s16x8 __attribute__((ext_vector_type(8)));

__device__ __forceinline__ ushort f2bf(float f) {          // setup-path only
    union { float f; unsigned u; } v; v.f = f;
    return (ushort)((v.u + 0x7FFFu + ((v.u >> 16) & 1u)) >> 16);
}
__device__ __forceinline__ float bf2f(ushort s) {
    union { unsigned u; float f; } v; v.u = ((unsigned)s) << 16; return v.f;
}
__device__ __forceinline__ unsigned pk2(float lo, float hi) {  // bf16(lo)|bf16(hi)<<16
    unsigned r;
    asm("v_cvt_pk_bf16_f32 %0, %1, %2" : "=v"(r) : "v"(lo), "v"(hi));
    return r;
}
__device__ __forceinline__ f32x4 MFMA(s16x8 a, s16x8 b, f32x4 c) {
    return __builtin_amdgcn_mfma_f32_16x16x32_bf16(a, b, c, 0, 0, 0);
}
__device__ __forceinline__ float eluf(float v) { return v > 0.f ? v : __expf(v) - 1.f; }

// B-fragment gather: dst[s][n] holds W[32s+8q+ii][uc0+n], n in {0,1}
__device__ __forceinline__ void load_wfrags(const float* __restrict__ W, int q, int uc0,
                                            s16x8 (&dst)[4][2]) {
#pragma unroll
    for (int s = 0; s < 4; ++s)
#pragma unroll
        for (int n = 0; n < 2; ++n) {
            s16x8 r;
#pragma unroll
            for (int ii = 0; ii < 8; ++ii)
                r[ii] = (short)f2bf(W[(32 * s + 8 * q + ii) * UDIM + uc0 + n]);
            dst[s][n] = r;
        }
}

// acc[m][n] += A(P)[16m+l15][k] * wB[s][n], k = 32s+8q+ii
template <int KSTEPS, int PITCH>
__device__ __forceinline__ void gemm_P(const ushort* __restrict__ P, const s16x8 (&wB)[KSTEPS][2],
                                       int l15, int q, f32x4 (&acc)[4][2]) {
#pragma unroll
    for (int s = 0; s < KSTEPS; ++s) {
        s16x8 a[4];
#pragma unroll
        for (int m = 0; m < 4; ++m)
            a[m] = *(const s16x8*)(P + (16 * m + l15) * PITCH + 32 * s + 8 * q);
#pragma unroll
        for (int m = 0; m < 4; ++m) {
            acc[m][0] = MFMA(a[m], wB[s][0], acc[m][0]);
            acc[m][1] = MFMA(a[m], wB[s][1], acc[m][1]);
        }
    }
}

// packed store: cols (uc0, uc0+1) as one b32 per row; 16 stores/thread
template <bool ELU>
__device__ __forceinline__ void store_P(ushort* __restrict__ P, const f32x4 (&v)[4][2],
                                        int q, int uc0) {
#pragma unroll
    for (int m = 0; m < 4; ++m)
#pragma unroll
        for (int r = 0; r < 4; ++r) {
            const int row = 16 * m + 4 * q + r;
            float a = v[m][0][r], c = v[m][1][r];
            if (ELU) { a = eluf(a); c = eluf(c); }
            *(unsigned*)(P + row * PP + uc0) = pk2(a, c);
        }
}

__global__ __launch_bounds__(256, 2) void egnn_mfma(
    const float* __restrict__ x, const float* __restrict__ h,
    const float* __restrict__ We1, const float* __restrict__ be1,
    const float* __restrict__ We2, const float* __restrict__ be2,
    const float* __restrict__ Winf, const float* __restrict__ binf,
    const float* __restrict__ Wx1, const float* __restrict__ bx1,
    const float* __restrict__ Wx2, const float* __restrict__ bx2,
    const float* __restrict__ Wx3, const float* __restrict__ bx3,
    const float* __restrict__ Wh1, const float* __restrict__ bh1,
    const float* __restrict__ Wh2, const float* __restrict__ bh2,
    const float* __restrict__ Wout, const float* __restrict__ bout,
    float* __restrict__ out) {
    __shared__ ushort F[JT][FP];      // h_j tile, bf16
    __shared__ ushort P1[JT][PP];     // ping (t1 / h1)
    __shared__ ushort P2[JT][PP];     // pong (m_ij / h2)
    __shared__ float normL[JT];
    __shared__ float diffL[JT][3];
    __shared__ float rpartE[4][JT];
    __shared__ float rpartP[4][JT];
    __shared__ float eL[JT];
    __shared__ float bias1L[UDIM];
    __shared__ float WinfL[UDIM], Wx3L[UDIM];
    __shared__ float catL[UDIM + HDIM];
    __shared__ float th1[UDIM], th2[UDIM];

    const int bi = blockIdx.x;
    const int b  = bi >> 9;
    const int i  = bi & (NN - 1);
    const int tid  = threadIdx.x;
    const int lane = tid & 63;
    const int w    = tid >> 6;
    const int l15  = lane & 15;
    const int q    = lane >> 4;
    const int uc0  = 32 * w + 2 * l15;     // adjacent output columns uc0, uc0+1

    // ---- per-block setup ----
    s16x8 wB1[2][2];
#pragma unroll
    for (int s = 0; s < 2; ++s)
#pragma unroll
        for (int n = 0; n < 2; ++n) {
            s16x8 r;
#pragma unroll
            for (int ii = 0; ii < 8; ++ii)
                r[ii] = (short)f2bf(We1[(1 + 32 * s + 8 * q + ii) * UDIM + uc0 + n]);
            wB1[s][n] = r;
        }
    s16x8 wB2[4][2], wB3[4][2], wB4[4][2];
    load_wfrags(We2, q, uc0, wB2);
    load_wfrags(Wx1, q, uc0, wB3);
    load_wfrags(Wx2, q, uc0, wB4);

    if (tid < UDIM) {
        WinfL[tid] = Winf[tid];
        Wx3L[tid]  = Wx3[tid];
        float s = be1[tid];
        const float* hi = &h[(b * NN + i) * HDIM];
#pragma unroll 8
        for (int k = 0; k < HDIM; ++k)
            s = fmaf(hi[k], We1[(1 + HDIM + k) * UDIM + tid], s);
        bias1L[tid] = s;                   // be1 + h_i @ We1[65:129]
    }
    const float w0n0 = We1[uc0], w0n1 = We1[uc0 + 1];
    const float b2n0 = be2[uc0], b2n1 = be2[uc0 + 1];
    const float bqn0 = bx1[uc0], bqn1 = bx1[uc0 + 1];
    const float brn0 = bx2[uc0], brn1 = bx2[uc0 + 1];
    const float binf0 = binf[0], bx30 = bx3[0];
    const float xi0 = x[(b * NN + i) * 3 + 0];
    const float xi1 = x[(b * NN + i) * 3 + 1];
    const float xi2 = x[(b * NN + i) * 3 + 2];
    __syncthreads();
    const float b1n0 = bias1L[uc0], b1n1 = bias1L[uc0 + 1];

    float mi0 = 0.f, mi1 = 0.f;
    float sh0 = 0.f, sh1 = 0.f, sh2 = 0.f;

    for (int t = 0; t < NTILE; ++t) {
        const int j0 = t * JT;
        __syncthreads();  // (A)

        // ---- stage h_j -> F (bf16 packed); diffs/norms ----
        {
            const int jr = tid >> 2, k0 = (tid & 3) * 16;
            const float* hp = &h[(b * NN + j0 + jr) * HDIM + k0];
            const float4 f0 = *(const float4*)hp;
            const float4 f1 = *(const float4*)(hp + 4);
            const float4 f2 = *(const float4*)(hp + 8);
            const float4 f3 = *(const float4*)(hp + 12);
            uint4 pv0, pv1;
            pv0.x = pk2(f0.x, f0.y); pv0.y = pk2(f0.z, f0.w);
            pv0.z = pk2(f1.x, f1.y); pv0.w = pk2(f1.z, f1.w);
            pv1.x = pk2(f2.x, f2.y); pv1.y = pk2(f2.z, f2.w);
            pv1.z = pk2(f3.x, f3.y); pv1.w = pk2(f3.z, f3.w);
            *(uint4*)&F[jr][k0]     = pv0;
            *(uint4*)&F[jr][k0 + 8] = pv1;
        }
        if (tid < JT) {
            const int j = j0 + tid;
            float d0 = x[(b * NN + j) * 3 + 0] - xi0;
            float d1 = x[(b * NN + j) * 3 + 1] - xi1;
            float d2 = x[(b * NN + j) * 3 + 2] - xi2;
            if (j == i) { d0 = 0.f; d1 = 0.f; d2 = 0.f; }
            diffL[tid][0] = d0; diffL[tid][1] = d1; diffL[tid][2] = d2;
            normL[tid] = (j == i) ? 0.f : sqrtf(d0 * d0 + d1 * d1 + d2 * d2);
        }
        __syncthreads();  // (B)

        // ---- GEMM1: t1 = elu(norm*We1r0 + h_j@We1[1:65] + bias1) ----
        f32x4 acc[4][2];
#pragma unroll
        for (int m = 0; m < 4; ++m)
#pragma unroll
            for (int r = 0; r < 4; ++r) {
                const float nrm = normL[16 * m + 4 * q + r];
                acc[m][0][r] = fmaf(nrm, w0n0, b1n0);
                acc[m][1][r] = fmaf(nrm, w0n1, b1n1);
            }
        gemm_P<2, FP>(&F[0][0], wB1, l15, q, acc);
        store_P<true>(&P1[0][0], acc, q, uc0);
        __syncthreads();  // (C)

        // ---- GEMM2: m_ij = t1@We2 + be2, diagonal-masked ----
        f32x4 macc[4][2];
#pragma unroll
        for (int m = 0; m < 4; ++m)
#pragma unroll
            for (int r = 0; r < 4; ++r) { macc[m][0][r] = b2n0; macc[m][1][r] = b2n1; }
        gemm_P<4, PP>(&P1[0][0], wB2, l15, q, macc);
#pragma unroll
        for (int m = 0; m < 4; ++m)
#pragma unroll
            for (int r = 0; r < 4; ++r)
                if (j0 + 16 * m + 4 * q + r == i) { macc[m][0][r] = 0.f; macc[m][1][r] = 0.f; }
        store_P<false>(&P2[0][0], macc, q, uc0);
        __syncthreads();  // (D)

        // ---- e partials (all threads, 32-u slice each) + GEMM3 ----
        {
            const int jj = tid & 63, sl = tid >> 6;
            const ushort* pr = &P2[jj][32 * sl];
            float p = 0.f;
#pragma unroll
            for (int cc = 0; cc < 4; ++cc) {
                const s16x8 mv = *(const s16x8*)(pr + 8 * cc);
#pragma unroll
                for (int c = 0; c < 8; ++c)
                    p = fmaf(bf2f((ushort)mv[c]), WinfL[32 * sl + 8 * cc + c], p);
            }
            rpartE[sl][jj] = p;
        }
        f32x4 qacc[4][2];
#pragma unroll
        for (int m = 0; m < 4; ++m)
#pragma unroll
            for (int r = 0; r < 4; ++r) { qacc[m][0][r] = bqn0; qacc[m][1][r] = bqn1; }
        gemm_P<4, PP>(&P2[0][0], wB3, l15, q, qacc);
        store_P<true>(&P1[0][0], qacc, q, uc0);
        __syncthreads();  // (E)

        // ---- e final (wave 0) ; GEMM4: h2 = elu(h1@Wx2+bx2) ----
        if (tid < JT) {
            float s = rpartE[0][tid] + rpartE[1][tid] + rpartE[2][tid] + rpartE[3][tid];
            float e = 1.f / (1.f + __expf(-(s + binf0)));
            if (j0 + tid == i) e = 0.f;
            eL[tid] = e;
        }
        f32x4 racc[4][2];
#pragma unroll
        for (int m = 0; m < 4; ++m)
#pragma unroll
            for (int r = 0; r < 4; ++r) { racc[m][0][r] = brn0; racc[m][1][r] = brn1; }
        gemm_P<4, PP>(&P1[0][0], wB4, l15, q, racc);
        store_P<true>(&P2[0][0], racc, q, uc0);
        __syncthreads();  // (F)

        // ---- phi partials ; m_i accumulation (fp32 register m_ij x eL) ----
        {
            const int jj = tid & 63, sl = tid >> 6;
            const ushort* pr = &P2[jj][32 * sl];
            float p = 0.f;
#pragma unroll
            for (int cc = 0; cc < 4; ++cc) {
                const s16x8 mv = *(const s16x8*)(pr + 8 * cc);
#pragma unroll
                for (int c = 0; c < 8; ++c)
                    p = fmaf(bf2f((ushort)mv[c]), Wx3L[32 * sl + 8 * cc + c], p);
            }
            rpartP[sl][jj] = p;
        }
#pragma unroll
        for (int m = 0; m < 4; ++m)
#pragma unroll
            for (int r = 0; r < 4; ++r) {
                const float e = eL[16 * m + 4 * q + r];
                mi0 = fmaf(macc[m][0][r], e, mi0);
                mi1 = fmaf(macc[m][1][r], e, mi1);
            }
        __syncthreads();  // (G)

        // ---- phi final + shift (wave 0, 64 rows, butterfly reduce) ----
        if (tid < JT) {
            float s = rpartP[0][tid] + rpartP[1][tid] + rpartP[2][tid] + rpartP[3][tid];
            s += bx30;
            if (j0 + tid == i) s = 0.f;
            float v0 = diffL[tid][0] * s;
            float v1 = diffL[tid][1] * s;
            float v2 = diffL[tid][2] * s;
#pragma unroll
            for (int d = 1; d < 64; d <<= 1) {
                v0 += __shfl_xor(v0, d);
                v1 += __shfl_xor(v1, d);
                v2 += __shfl_xor(v2, d);
            }
            sh0 += v0; sh1 += v1; sh2 += v2;
        }
    }

    __syncthreads();
    // ---- m_i cross-quarter reduce -> catL ----
    {
        float v0 = mi0, v1 = mi1;
        v0 += __shfl_xor(v0, 16); v0 += __shfl_xor(v0, 32);
        v1 += __shfl_xor(v1, 16); v1 += __shfl_xor(v1, 32);
        if (lane < 16) {
            catL[uc0]     = v0;
            catL[uc0 + 1] = v1;
        }
    }
    if (tid >= 128 && tid < 128 + HDIM)
        catL[UDIM + tid - 128] = h[(b * NN + i) * HDIM + (tid - 128)];
    if (tid == 0) {
        const float inv = 1.f / (float)(NN - 1);
        out[(b * NN + i) * 3 + 0] = x[(b * NN + i) * 3 + 0] + sh0 * inv;
        out[(b * NN + i) * 3 + 1] = x[(b * NN + i) * 3 + 1] + sh1 * inv;
        out[(b * NN + i) * 3 + 2] = x[(b * NN + i) * 3 + 2] + sh2 * inv;
    }
    __syncthreads();

    // ---- h-MLP epilogue (fp32) ----
    if (tid < UDIM) {
        float s = bh1[tid];
        for (int k = 0; k < UDIM + HDIM; ++k) s = fmaf(catL[k], Wh1[k * UDIM + tid], s);
        th1[tid] = eluf(s);
    }
    __syncthreads();
    if (tid < UDIM) {
        float s = bh2[tid];
        for (int k = 0; k < UDIM; ++k) s = fmaf(th1[k], Wh2[k * UDIM + tid], s);
        th2[tid] = s;
    }
    __syncthreads();
    if (tid < HDIM) {
        float s = bout[tid];
        for (int k = 0; k < UDIM; ++k) s = fmaf(th2[k], Wout[k * HDIM + tid], s);
        out[BB * NN * 3 + (b * NN + i) * HDIM + tid] = s;
    }
}

extern "C" void kernel_launch(void* const* d_in, const int* in_sizes, int n_in,
                              void* d_out, int out_size, void* d_ws, size_t ws_size,
                              hipStream_t stream) {
    const float* x    = (const float*)d_in[0];
    const float* h    = (const float*)d_in[1];
    const float* We1  = (const float*)d_in[2];
    const float* be1  = (const float*)d_in[3];
    const float* We2  = (const float*)d_in[4];
    const float* be2  = (const float*)d_in[5];
    const float* Winf = (const float*)d_in[6];
    const float* binf = (const float*)d_in[7];
    const float* Wx1  = (const float*)d_in[8];
    const float* bx1  = (const float*)d_in[9];
    const float* Wx2  = (const float*)d_in[10];
    const float* bx2  = (const float*)d_in[11];
    const float* Wx3  = (const float*)d_in[12];
    const float* bx3  = (const float*)d_in[13];
    const float* Wh1  = (const float*)d_in[14];
    const float* bh1  = (const float*)d_in[15];
    const float* Wh2  = (const float*)d_in[16];
    const float* bh2  = (const float*)d_in[17];
    const float* Wout = (const float*)d_in[18];
    const float* bout = (const float*)d_in[19];
    float* out = (float*)d_out;

    hipLaunchKernelGGL(egnn_mfma, dim3(BB * NN), dim3(256), 0, stream,
                       x, h, We1, be1, We2, be2, Winf, binf, Wx1, bx1, Wx2, bx2,
                       Wx3, bx3, Wh1, bh1, Wh2, bh2, Wout, bout, out);
}